// Round 10
// baseline (122.010 us; speedup 1.0000x reference)
//
#include <hip/hip_runtime.h>
#include <stdint.h>

#define N_NODES 8192
#define N_EDGES 65536
#define N_TRIPLES (N_EDGES + N_NODES)   // 73728
#define D 768
#define D2 1536
#define NREL 38
#define BATCH 8
#define SENTN 512                        // B*S
#define OUT1_OFF ((size_t)N_TRIPLES * D)                     // 56623104
#define OUT2_OFF (OUT1_OFF + (size_t)BATCH * N_TRIPLES)      // 57212928

typedef __attribute__((ext_vector_type(8))) __bf16 bf16x8;
typedef __attribute__((ext_vector_type(4))) float f32x4;
typedef __attribute__((ext_vector_type(4))) unsigned short ushort4v;

static __device__ __forceinline__ unsigned short f2bf(float f) {
  unsigned u = __builtin_bit_cast(unsigned, f);
  u += 0x7FFFu + ((u >> 16) & 1u);
  return (unsigned short)(u >> 16);
}
static __device__ __forceinline__ float bf2f(unsigned short h) {
  return __builtin_bit_cast(float, ((unsigned)h) << 16);
}

// ================= merged prep (R5 + 64 head-count blocks) =================
__global__ void k_prep(const int* __restrict__ cids, const float* __restrict__ cemb,
                       unsigned short* __restrict__ xbf,
                       const float* __restrict__ W, unsigned short* __restrict__ wt,
                       const float* __restrict__ relemb, const float* __restrict__ selfemb,
                       float* __restrict__ partials,
                       const int* __restrict__ sent, unsigned int* __restrict__ nmask,
                       const int* __restrict__ eidx, int* __restrict__ counts) {
  __shared__ __align__(16) char smraw[32 * 33 * 4];
  int b = blockIdx.x;
  if (b < 6144) {
    int t4 = b * 256 + threadIdx.x;
    int row = t4 / (D / 4);
    int c4 = t4 % (D / 4);
    int cid = cids[row];
    float4 v = ((const float4*)(cemb + (size_t)cid * D))[c4];
    ushort4v o;
    o.x = f2bf(v.x); o.y = f2bf(v.y); o.z = f2bf(v.z); o.w = f2bf(v.w);
    *(ushort4v*)(xbf + (size_t)t4 * 4) = o;
  } else if (b < 7296) {
    float (*tile)[33] = (float(*)[33])smraw;
    int idx = b - 6144;
    int kb = (idx % 24) * 32;
    int jb = (idx / 24) * 32;
    int tx = threadIdx.x % 32;
    int ty = threadIdx.x / 32;
#pragma unroll
    for (int i = 0; i < 4; ++i) {
      int k = kb + ty + i * 8;
      int j = jb + tx;
      float v = (j < D) ? W[(size_t)k * D + j] : W[(size_t)(2 * D + k) * D + (j - D)];
      tile[ty + i * 8][tx] = v;
    }
    __syncthreads();
#pragma unroll
    for (int i = 0; i < 4; ++i) {
      int j = jb + ty + i * 8;
      int k = kb + tx;
      wt[(size_t)j * D + k] = f2bf(tile[tx][ty + i * 8]);
    }
  } else if (b < 7530) {
    int idx = b - 7296;        // 0..233
    int r = idx / 6;           // 0..38
    int ch = idx % 6;          // K-chunk of 128
    const float* src = (r < NREL) ? (relemb + (size_t)r * D) : selfemb;
    int c = threadIdx.x;
    const float* W2 = W + (size_t)D * D;
    float a0 = 0.f, a1 = 0.f, a2 = 0.f;
    int k0 = ch * 128;
    for (int k = 0; k < 128; ++k) {
      float s = src[k0 + k];
      const float* wr = W2 + (size_t)(k0 + k) * D;
      a0 += s * wr[c];
      a1 += s * wr[c + 256];
      a2 += s * wr[c + 512];
    }
    float* p = partials + (size_t)idx * D;
    p[c] = a0;
    p[c + 256] = a1;
    p[c + 512] = a2;
  } else if (b < 7562) {
    int* ls = (int*)smraw;
    for (int i = threadIdx.x; i < SENTN; i += 256) ls[i] = sent[i];
    __syncthreads();
    int n = (b - 7530) * 256 + threadIdx.x;
    int cid = cids[n];
    unsigned m = 0;
#pragma unroll 16
    for (int s = 0; s < SENTN; ++s)
      m |= (ls[s] == cid) ? (1u << (s >> 6)) : 0u;
    nmask[n] = m;
  } else {
    // ---- head-degree histogram: 64 blocks x 256 thr x 4 edges ----
    int e0 = (b - 7562) * 1024 + threadIdx.x * 4;
#pragma unroll
    for (int q = 0; q < 4; ++q)
      atomicAdd(&counts[eidx[e0 + q]], 1);
  }
}

// ================= exclusive scan of 8192 head counts -> cursor =================
__global__ void k_scan(const int* __restrict__ counts, int* __restrict__ cursor) {
  __shared__ int part[1024];
  int tid = threadIdx.x;
  int v[8];
  int s = 0;
#pragma unroll
  for (int i = 0; i < 8; ++i) {
    v[i] = counts[tid * 8 + i];
    s += v[i];
  }
  part[tid] = s;
  __syncthreads();
  for (int off = 1; off < 1024; off <<= 1) {
    int t = (tid >= off) ? part[tid - off] : 0;
    __syncthreads();
    part[tid] += t;
    __syncthreads();
  }
  int ex = tid ? part[tid - 1] : 0;
#pragma unroll
  for (int i = 0; i < 8; ++i) {
    cursor[tid * 8 + i] = ex;
    ex += v[i];
  }
}

// ================= GEMM (R5-exact) + side work + scatter =================
__global__ void k_gemm(const unsigned short* __restrict__ A,
                       const unsigned short* __restrict__ BT,
                       unsigned short* __restrict__ Cb,
                       const float* __restrict__ partials, float* __restrict__ relw2,
                       const float* __restrict__ bias,
                       const int* __restrict__ cids, const int* __restrict__ eidx,
                       const float* __restrict__ eattr, const unsigned* __restrict__ nmask,
                       int* __restrict__ cursor, int* __restrict__ order,
                       float* __restrict__ out) {
  __shared__ __align__(16) unsigned short lsAB[2][2][128 * 64];   // [buf][A/B]
  const int bid = blockIdx.x;
  const int tid = threadIdx.x;

  if (bid >= 768) {
    if (bid < 807) {
      int r = bid - 768;
      int c = tid;
      const float* p = partials + (size_t)r * 6 * D;
#pragma unroll
      for (int j = 0; j < 3; ++j) {
        int cc = c + j * 256;
        float s = 0.f;
#pragma unroll
        for (int ch = 0; ch < 6; ++ch) s += p[(size_t)ch * D + cc];
        relw2[(size_t)r * D + cc] = s;
      }
    } else if (bid < 1095) {
      int t = (bid - 807) * 256 + tid;
      int h, tl;
      float rel;
      if (t < N_EDGES) {
        h = eidx[t];
        tl = eidx[N_EDGES + t];
        rel = (float)(int)eattr[2 * t];
      } else {
        h = t - N_EDGES;
        tl = h;
        rel = (float)NREL;
      }
      float* o2 = out + OUT2_OFF + (size_t)t * 3;
      __builtin_nontemporal_store((float)cids[h], o2 + 0);
      __builtin_nontemporal_store(rel, o2 + 1);
      __builtin_nontemporal_store((float)cids[tl], o2 + 2);
      unsigned m = nmask[h] | nmask[tl];
      float* o1 = out + OUT1_OFF;
#pragma unroll
      for (int bb = 0; bb < BATCH; ++bb)
        __builtin_nontemporal_store(((m >> bb) & 1u) ? 1.0f : 0.0f,
                                    o1 + (size_t)bb * N_TRIPLES + t);
    } else {
      // ---- scatter edges into head-sorted order ----
      int e0 = (bid - 1095) * 1024 + tid * 4;
#pragma unroll
      for (int q = 0; q < 4; ++q) {
        int e = e0 + q;
        int pos = atomicAdd(&cursor[eidx[e]], 1);
        order[pos] = e;
      }
    }
    return;
  }

  const int lane = tid & 63;
  const int wid = tid >> 6;
  const int wr = wid >> 1, wc = wid & 1;

  const int swz = (bid & 7) * 96 + (bid >> 3);
  const int arow0 = (swz / 12) * 128;
  const int bcol0 = (swz % 12) * 128;

  f32x4 acc[4][4] = {};

  const int rloc = tid >> 3;
  const int gchunk = (tid & 7) ^ (rloc & 7);
  const unsigned short* ga = A + (size_t)(arow0 + rloc) * D + gchunk * 8;
  const unsigned short* gb = BT + (size_t)(bcol0 + rloc) * D + gchunk * 8;
  const int lbo = (tid & ~63) * 8;

  const int lr = lane & 15;
  const int hi = lane >> 4;

#define STAGE(BUF, K0)                                                                 \
  {                                                                                    \
    unsigned short* dA = &lsAB[BUF][0][lbo];                                           \
    unsigned short* dB = &lsAB[BUF][1][lbo];                                           \
    _Pragma("unroll") for (int c = 0; c < 4; ++c) {                                    \
      __builtin_amdgcn_global_load_lds(                                                \
          (const __attribute__((address_space(1))) void*)(ga + (size_t)c * 32 * D + (K0)), \
          (__attribute__((address_space(3))) void*)(dA + c * 2048), 16, 0, 0);         \
      __builtin_amdgcn_global_load_lds(                                                \
          (const __attribute__((address_space(1))) void*)(gb + (size_t)c * 32 * D + (K0)), \
          (__attribute__((address_space(3))) void*)(dB + c * 2048), 16, 0, 0);         \
    }                                                                                  \
  }

#define COMPUTE(BUF)                                                                   \
  {                                                                                    \
    const unsigned short* sA = lsAB[BUF][0];                                           \
    const unsigned short* sB = lsAB[BUF][1];                                           \
    _Pragma("unroll") for (int kk = 0; kk < 2; ++kk) {                                 \
      const int swc = ((kk * 4 + hi) ^ (lr & 7)) * 8;                                  \
      bf16x8 af[4], bfr[4];                                                            \
      _Pragma("unroll") for (int m = 0; m < 4; ++m)                                    \
          af[m] = *(const bf16x8*)(sA + (wr * 64 + m * 16 + lr) * 64 + swc);           \
      _Pragma("unroll") for (int n = 0; n < 4; ++n)                                    \
          bfr[n] = *(const bf16x8*)(sB + (wc * 64 + n * 16 + lr) * 64 + swc);          \
      _Pragma("unroll") for (int m = 0; m < 4; ++m)                                    \
          _Pragma("unroll") for (int n = 0; n < 4; ++n)                                \
              acc[m][n] = __builtin_amdgcn_mfma_f32_16x16x32_bf16(af[m], bfr[n],       \
                                                                  acc[m][n], 0, 0, 0); \
    }                                                                                  \
  }

  STAGE(0, 0)
  STAGE(1, 64)
#pragma unroll
  for (int t = 0; t < 12; ++t) {
    if (t < 11) { asm volatile("s_waitcnt vmcnt(8)" ::: "memory"); }
    else        { asm volatile("s_waitcnt vmcnt(0)" ::: "memory"); }
    __builtin_amdgcn_s_barrier();
    if (t & 1) COMPUTE(1) else COMPUTE(0)
    asm volatile("" ::: "memory");
    __builtin_amdgcn_s_barrier();
    if (t + 2 < 12) { if (t & 1) STAGE(1, (t + 2) * 64) else STAGE(0, (t + 2) * 64) }
  }
#undef STAGE
#undef COMPUTE

  const int crow = hi * 4;
  const int ccol = lr;
  const bool addb = (bcol0 < D);
#pragma unroll
  for (int m = 0; m < 4; ++m) {
    int row = arow0 + wr * 64 + m * 16 + crow;
#pragma unroll
    for (int n = 0; n < 4; ++n) {
      int col = bcol0 + wc * 64 + n * 16 + ccol;
      float bv = addb ? bias[col] : 0.f;
      unsigned short* cp = Cb + (size_t)row * D2 + col;
#pragma unroll
      for (int r = 0; r < 4; ++r)
        cp[(size_t)r * D2] = f2bf(acc[m][n][r] + bv);
    }
  }
}

// ================= encoded output =================
// blocks [0,4096): edges in HEAD-SORTED order (via order[]) -> each head row
//   xw1[h] is read by consecutive waves (deg~9) => L2/L3 hit instead of 113MB
//   of unique fabric reads. Output row = original edge id (values identical
//   regardless of processing order => deterministic output).
// blocks [4096,4608): self-loop triples (already head-sequential).
__global__ void k_out(const int* __restrict__ eidx, const float* __restrict__ eattr,
                      const int* __restrict__ order,
                      const unsigned short* __restrict__ xwb, const float* __restrict__ relw2,
                      float* __restrict__ out) {
  const int wid = threadIdx.x >> 6;
  const int lane = threadIdx.x & 63;

  int tq[4];
  const ushort4v* r1[4];
  const ushort4v* r3[4];
  const f32x4* rw[4];
  float w[4];

  if (blockIdx.x < 4096) {
    const int s0 = blockIdx.x * 16 + wid * 4;
#pragma unroll
    for (int q = 0; q < 4; ++q) {
      int e = order[s0 + q];
      tq[q] = e;
      int h = eidx[e];
      int tl = eidx[N_EDGES + e];
      int rel = (int)eattr[2 * e];
      w[q] = eattr[2 * e + 1];
      r1[q] = (const ushort4v*)(xwb + (size_t)h * D2);
      r3[q] = (const ushort4v*)(xwb + (size_t)tl * D2 + D);
      rw[q] = (const f32x4*)(relw2 + (size_t)rel * D);
    }
  } else {
    const int i0 = (blockIdx.x - 4096) * 16 + wid * 4;
#pragma unroll
    for (int q = 0; q < 4; ++q) {
      int i = i0 + q;
      tq[q] = N_EDGES + i;
      w[q] = 1.f;
      r1[q] = (const ushort4v*)(xwb + (size_t)i * D2);
      r3[q] = (const ushort4v*)(xwb + (size_t)i * D2 + D);
      rw[q] = (const f32x4*)(relw2 + (size_t)NREL * D);
    }
  }

#pragma unroll
  for (int j = 0; j < 3; ++j) {
    const int c4 = j * 64 + lane;
    ushort4v a4[4], x4[4];
    f32x4 c[4];
#pragma unroll
    for (int q = 0; q < 4; ++q) {
      a4[q] = r1[q][c4];
      x4[q] = r3[q][c4];
      c[q] = rw[q][c4];
    }
#pragma unroll
    for (int q = 0; q < 4; ++q) {
      f32x4 res;
      res.x = bf2f(a4[q].x) + w[q] * c[q].x + bf2f(x4[q].x);
      res.y = bf2f(a4[q].y) + w[q] * c[q].y + bf2f(x4[q].y);
      res.z = bf2f(a4[q].z) + w[q] * c[q].z + bf2f(x4[q].z);
      res.w = bf2f(a4[q].w) + w[q] * c[q].w + bf2f(x4[q].w);
      f32x4* o = (f32x4*)(out + (size_t)tq[q] * D);
      __builtin_nontemporal_store(res, &o[c4]);
    }
  }
}

extern "C" void kernel_launch(void* const* d_in, const int* in_sizes, int n_in,
                              void* d_out, int out_size, void* d_ws, size_t ws_size,
                              hipStream_t stream) {
  const int* cids = (const int*)d_in[0];
  const int* eidx = (const int*)d_in[1];
  const float* eattr = (const float*)d_in[2];
  const int* sent = (const int*)d_in[3];
  const float* cemb = (const float*)d_in[4];
  const float* relemb = (const float*)d_in[5];
  const float* selfemb = (const float*)d_in[6];
  const float* W = (const float*)d_in[7];
  const float* bias = (const float*)d_in[8];

  char* ws = (char*)d_ws;
  unsigned short* xbf = (unsigned short*)ws;                                   // 12,582,912
  unsigned short* wt = (unsigned short*)(ws + 12582912);                       //  2,359,296
  unsigned short* xwb = (unsigned short*)(ws + 12582912 + 2359296);            // 25,165,824
  float* relw2 = (float*)(ws + 40108032);                                      //    119,808
  unsigned* nmask = (unsigned*)(ws + 40108032 + 119808);                       //     32,768
  float* partials = (float*)(ws + 40108032 + 119808 + 32768);                  //    718,848
  int* counts = (int*)(ws + 40108032 + 119808 + 32768 + 718848);               //     32,768
  int* cursor = (int*)(ws + 40108032 + 119808 + 32768 + 718848 + 32768);       //     32,768
  int* order = (int*)(ws + 40108032 + 119808 + 32768 + 718848 + 65536);        //    262,144

  float* out = (float*)d_out;

  hipMemsetAsync(counts, 0, 32768, stream);
  k_prep<<<dim3(7626), dim3(256), 0, stream>>>(cids, cemb, xbf, W, wt, relemb, selfemb,
                                               partials, sent, nmask, eidx, counts);
  k_scan<<<dim3(1), dim3(1024), 0, stream>>>(counts, cursor);
  k_gemm<<<dim3(1159), dim3(256), 0, stream>>>(xbf, wt, xwb, partials, relw2, bias,
                                               cids, eidx, eattr, nmask, cursor, order, out);
  k_out<<<dim3(4608), dim3(256), 0, stream>>>(eidx, eattr, order, xwb, relw2, out);
}

// Round 11
// 101.530 us; speedup vs baseline: 1.2017x; 1.2017x over previous
//
#include <hip/hip_runtime.h>
#include <stdint.h>

#define N_NODES 8192
#define N_EDGES 65536
#define N_TRIPLES (N_EDGES + N_NODES)   // 73728
#define D 768
#define D2 1536
#define NREL 38
#define BATCH 8
#define SENTN 512                        // B*S
#define OUT1_OFF ((size_t)N_TRIPLES * D)                     // 56623104
#define OUT2_OFF (OUT1_OFF + (size_t)BATCH * N_TRIPLES)      // 57212928

typedef __attribute__((ext_vector_type(8))) __bf16 bf16x8;
typedef __attribute__((ext_vector_type(4))) float f32x4;
typedef __attribute__((ext_vector_type(2))) float f32x2;
typedef __attribute__((ext_vector_type(4))) unsigned short ushort4v;

static __device__ __forceinline__ unsigned short f2bf(float f) {
  unsigned u = __builtin_bit_cast(unsigned, f);
  u += 0x7FFFu + ((u >> 16) & 1u);
  return (unsigned short)(u >> 16);
}

// ================= merged prep (R5-exact) =================
__global__ void k_prep(const int* __restrict__ cids, const float* __restrict__ cemb,
                       unsigned short* __restrict__ xbf,
                       const float* __restrict__ W, unsigned short* __restrict__ wt,
                       const float* __restrict__ relemb, const float* __restrict__ selfemb,
                       float* __restrict__ partials,
                       const int* __restrict__ sent, unsigned int* __restrict__ nmask) {
  __shared__ __align__(16) char smraw[32 * 33 * 4];
  int b = blockIdx.x;
  if (b < 6144) {
    int t4 = b * 256 + threadIdx.x;
    int row = t4 / (D / 4);
    int c4 = t4 % (D / 4);
    int cid = cids[row];
    float4 v = ((const float4*)(cemb + (size_t)cid * D))[c4];
    ushort4v o;
    o.x = f2bf(v.x); o.y = f2bf(v.y); o.z = f2bf(v.z); o.w = f2bf(v.w);
    *(ushort4v*)(xbf + (size_t)t4 * 4) = o;
  } else if (b < 7296) {
    float (*tile)[33] = (float(*)[33])smraw;
    int idx = b - 6144;
    int kb = (idx % 24) * 32;
    int jb = (idx / 24) * 32;
    int tx = threadIdx.x % 32;
    int ty = threadIdx.x / 32;
#pragma unroll
    for (int i = 0; i < 4; ++i) {
      int k = kb + ty + i * 8;
      int j = jb + tx;
      float v = (j < D) ? W[(size_t)k * D + j] : W[(size_t)(2 * D + k) * D + (j - D)];
      tile[ty + i * 8][tx] = v;
    }
    __syncthreads();
#pragma unroll
    for (int i = 0; i < 4; ++i) {
      int j = jb + ty + i * 8;
      int k = kb + tx;
      wt[(size_t)j * D + k] = f2bf(tile[tx][ty + i * 8]);
    }
  } else if (b < 7530) {
    int idx = b - 7296;        // 0..233
    int r = idx / 6;           // 0..38
    int ch = idx % 6;          // K-chunk of 128
    const float* src = (r < NREL) ? (relemb + (size_t)r * D) : selfemb;
    int c = threadIdx.x;
    const float* W2 = W + (size_t)D * D;
    float a0 = 0.f, a1 = 0.f, a2 = 0.f;
    int k0 = ch * 128;
    for (int k = 0; k < 128; ++k) {
      float s = src[k0 + k];
      const float* wr = W2 + (size_t)(k0 + k) * D;
      a0 += s * wr[c];
      a1 += s * wr[c + 256];
      a2 += s * wr[c + 512];
    }
    float* p = partials + (size_t)idx * D;
    p[c] = a0;
    p[c + 256] = a1;
    p[c + 512] = a2;
  } else {
    int* ls = (int*)smraw;
    for (int i = threadIdx.x; i < SENTN; i += 256) ls[i] = sent[i];
    __syncthreads();
    int n = (b - 7530) * 256 + threadIdx.x;
    int cid = cids[n];
    unsigned m = 0;
#pragma unroll 16
    for (int s = 0; s < SENTN; ++s)
      m |= (ls[s] == cid) ? (1u << (s >> 6)) : 0u;
    nmask[n] = m;
  }
}

// ================= GEMM + side work (R5 main loop; fp8 C-write) =================
__global__ void k_gemm(const unsigned short* __restrict__ A,
                       const unsigned short* __restrict__ BT,
                       unsigned char* __restrict__ xw8,
                       const float* __restrict__ partials, float* __restrict__ relw2,
                       const float* __restrict__ bias,
                       const int* __restrict__ cids, const int* __restrict__ eidx,
                       const float* __restrict__ eattr, const unsigned* __restrict__ nmask,
                       float* __restrict__ out) {
  __shared__ __align__(16) unsigned short lsAB[2][2][128 * 64];   // [buf][A/B]
  const int bid = blockIdx.x;
  const int tid = threadIdx.x;

  if (bid >= 768) {
    if (bid < 807) {
      int r = bid - 768;
      int c = tid;
      const float* p = partials + (size_t)r * 6 * D;
#pragma unroll
      for (int j = 0; j < 3; ++j) {
        int cc = c + j * 256;
        float s = 0.f;
#pragma unroll
        for (int ch = 0; ch < 6; ++ch) s += p[(size_t)ch * D + cc];
        relw2[(size_t)r * D + cc] = s;
      }
    } else {
      int t = (bid - 807) * 256 + tid;
      int h, tl;
      float rel;
      if (t < N_EDGES) {
        h = eidx[t];
        tl = eidx[N_EDGES + t];
        rel = (float)(int)eattr[2 * t];
      } else {
        h = t - N_EDGES;
        tl = h;
        rel = (float)NREL;
      }
      float* o2 = out + OUT2_OFF + (size_t)t * 3;
      __builtin_nontemporal_store((float)cids[h], o2 + 0);
      __builtin_nontemporal_store(rel, o2 + 1);
      __builtin_nontemporal_store((float)cids[tl], o2 + 2);
      unsigned m = nmask[h] | nmask[tl];
      float* o1 = out + OUT1_OFF;
#pragma unroll
      for (int bb = 0; bb < BATCH; ++bb)
        __builtin_nontemporal_store(((m >> bb) & 1u) ? 1.0f : 0.0f,
                                    o1 + (size_t)bb * N_TRIPLES + t);
    }
    return;
  }

  const int lane = tid & 63;
  const int wid = tid >> 6;
  const int wr = wid >> 1, wc = wid & 1;

  const int swz = (bid & 7) * 96 + (bid >> 3);
  const int arow0 = (swz / 12) * 128;
  const int bcol0 = (swz % 12) * 128;

  f32x4 acc[4][4] = {};

  const int rloc = tid >> 3;
  const int gchunk = (tid & 7) ^ (rloc & 7);
  const unsigned short* ga = A + (size_t)(arow0 + rloc) * D + gchunk * 8;
  const unsigned short* gb = BT + (size_t)(bcol0 + rloc) * D + gchunk * 8;
  const int lbo = (tid & ~63) * 8;

  const int lr = lane & 15;
  const int hi = lane >> 4;

#define STAGE(BUF, K0)                                                                 \
  {                                                                                    \
    unsigned short* dA = &lsAB[BUF][0][lbo];                                           \
    unsigned short* dB = &lsAB[BUF][1][lbo];                                           \
    _Pragma("unroll") for (int c = 0; c < 4; ++c) {                                    \
      __builtin_amdgcn_global_load_lds(                                                \
          (const __attribute__((address_space(1))) void*)(ga + (size_t)c * 32 * D + (K0)), \
          (__attribute__((address_space(3))) void*)(dA + c * 2048), 16, 0, 0);         \
      __builtin_amdgcn_global_load_lds(                                                \
          (const __attribute__((address_space(1))) void*)(gb + (size_t)c * 32 * D + (K0)), \
          (__attribute__((address_space(3))) void*)(dB + c * 2048), 16, 0, 0);         \
    }                                                                                  \
  }

#define COMPUTE(BUF)                                                                   \
  {                                                                                    \
    const unsigned short* sA = lsAB[BUF][0];                                           \
    const unsigned short* sB = lsAB[BUF][1];                                           \
    _Pragma("unroll") for (int kk = 0; kk < 2; ++kk) {                                 \
      const int swc = ((kk * 4 + hi) ^ (lr & 7)) * 8;                                  \
      bf16x8 af[4], bfr[4];                                                            \
      _Pragma("unroll") for (int m = 0; m < 4; ++m)                                    \
          af[m] = *(const bf16x8*)(sA + (wr * 64 + m * 16 + lr) * 64 + swc);           \
      _Pragma("unroll") for (int n = 0; n < 4; ++n)                                    \
          bfr[n] = *(const bf16x8*)(sB + (wc * 64 + n * 16 + lr) * 64 + swc);          \
      _Pragma("unroll") for (int m = 0; m < 4; ++m)                                    \
          _Pragma("unroll") for (int n = 0; n < 4; ++n)                                \
              acc[m][n] = __builtin_amdgcn_mfma_f32_16x16x32_bf16(af[m], bfr[n],       \
                                                                  acc[m][n], 0, 0, 0); \
    }                                                                                  \
  }

  STAGE(0, 0)
  STAGE(1, 64)
#pragma unroll
  for (int t = 0; t < 12; ++t) {
    if (t < 11) { asm volatile("s_waitcnt vmcnt(8)" ::: "memory"); }
    else        { asm volatile("s_waitcnt vmcnt(0)" ::: "memory"); }
    __builtin_amdgcn_s_barrier();
    if (t & 1) COMPUTE(1) else COMPUTE(0)
    asm volatile("" ::: "memory");
    __builtin_amdgcn_s_barrier();
    if (t + 2 < 12) { if (t & 1) STAGE(1, (t + 2) * 64) else STAGE(0, (t + 2) * 64) }
  }
#undef STAGE
#undef COMPUTE

  // Epilogue: bias fold (cols<768, unscaled term) + fp8 e4m3 pack via HW cvt.
  // Encode/decode use the paired gfx950 instructions -> format round-trip exact.
  const int crow = hi * 4;
  const int ccol = lr;
  const bool addb = (bcol0 < D);
#pragma unroll
  for (int m = 0; m < 4; ++m) {
    int row = arow0 + wr * 64 + m * 16 + crow;
#pragma unroll
    for (int n = 0; n < 4; ++n) {
      int col = bcol0 + wc * 64 + n * 16 + ccol;
      float bv = addb ? bias[col] : 0.f;
      unsigned char* cp = xw8 + (size_t)row * D2 + col;
      int p01 = __builtin_amdgcn_cvt_pk_fp8_f32(acc[m][n][0] + bv, acc[m][n][1] + bv, 0, false);
      int p23 = __builtin_amdgcn_cvt_pk_fp8_f32(acc[m][n][2] + bv, acc[m][n][3] + bv, 0, false);
      cp[0] = (unsigned char)(p01 & 0xFF);
      cp[(size_t)1 * D2] = (unsigned char)((p01 >> 8) & 0xFF);
      cp[(size_t)2 * D2] = (unsigned char)(p23 & 0xFF);
      cp[(size_t)3 * D2] = (unsigned char)((p23 >> 8) & 0xFF);
    }
  }
}

// ================= encoded output (R5 structure; fp8 gather decode) =================
// encoded[t] = xw1b[head] + w*relW2[rel] + xw3[tail]; xw rows are fp8 e4m3.
// Gather bytes halved: 226MB -> 113MB on the fabric.
__global__ void k_out(const int* __restrict__ eidx, const float* __restrict__ eattr,
                      const unsigned char* __restrict__ xw8, const float* __restrict__ relw2,
                      float* __restrict__ out) {
  const int wid = threadIdx.x >> 6;
  const int lane = threadIdx.x & 63;
  const int t0 = blockIdx.x * 16 + wid * 4;

  const unsigned* r1[4];
  const unsigned* r3[4];
  const f32x4* rw[4];
  float w[4];
#pragma unroll
  for (int q = 0; q < 4; ++q) {
    int t = t0 + q;
    if (t < N_EDGES) {
      int h = eidx[t];
      int tl = eidx[N_EDGES + t];
      int rel = (int)eattr[2 * t];
      w[q] = eattr[2 * t + 1];
      r1[q] = (const unsigned*)(xw8 + (size_t)h * D2);
      r3[q] = (const unsigned*)(xw8 + (size_t)tl * D2 + D);
      rw[q] = (const f32x4*)(relw2 + (size_t)rel * D);
    } else {
      int i = t - N_EDGES;
      w[q] = 1.f;
      r1[q] = (const unsigned*)(xw8 + (size_t)i * D2);
      r3[q] = (const unsigned*)(xw8 + (size_t)i * D2 + D);
      rw[q] = (const f32x4*)(relw2 + (size_t)NREL * D);
    }
  }

#pragma unroll
  for (int j = 0; j < 3; ++j) {
    const int c4 = j * 64 + lane;
    unsigned ua[4], ux[4];
    f32x4 c[4];
#pragma unroll
    for (int q = 0; q < 4; ++q) {
      ua[q] = r1[q][c4];
      ux[q] = r3[q][c4];
      c[q] = rw[q][c4];
    }
#pragma unroll
    for (int q = 0; q < 4; ++q) {
      f32x2 alo = __builtin_amdgcn_cvt_pk_f32_fp8(ua[q], false);
      f32x2 ahi = __builtin_amdgcn_cvt_pk_f32_fp8(ua[q], true);
      f32x2 xlo = __builtin_amdgcn_cvt_pk_f32_fp8(ux[q], false);
      f32x2 xhi = __builtin_amdgcn_cvt_pk_f32_fp8(ux[q], true);
      f32x4 res;
      res.x = alo[0] + w[q] * c[q].x + xlo[0];
      res.y = alo[1] + w[q] * c[q].y + xlo[1];
      res.z = ahi[0] + w[q] * c[q].z + xhi[0];
      res.w = ahi[1] + w[q] * c[q].w + xhi[1];
      f32x4* o = (f32x4*)(out + (size_t)(t0 + q) * D);
      __builtin_nontemporal_store(res, &o[c4]);
    }
  }
}

extern "C" void kernel_launch(void* const* d_in, const int* in_sizes, int n_in,
                              void* d_out, int out_size, void* d_ws, size_t ws_size,
                              hipStream_t stream) {
  const int* cids = (const int*)d_in[0];
  const int* eidx = (const int*)d_in[1];
  const float* eattr = (const float*)d_in[2];
  const int* sent = (const int*)d_in[3];
  const float* cemb = (const float*)d_in[4];
  const float* relemb = (const float*)d_in[5];
  const float* selfemb = (const float*)d_in[6];
  const float* W = (const float*)d_in[7];
  const float* bias = (const float*)d_in[8];

  char* ws = (char*)d_ws;
  unsigned short* xbf = (unsigned short*)ws;                         // 12,582,912 B
  unsigned short* wt = (unsigned short*)(ws + 12582912);             //  2,359,296 B
  unsigned char* xw8 = (unsigned char*)(ws + 12582912 + 2359296);    // 12,582,912 B (fp8)
  float* relw2 = (float*)(ws + 40108032);                            //    119,808 B
  unsigned* nmask = (unsigned*)(ws + 40108032 + 119808);             //     32,768 B
  float* partials = (float*)(ws + 40108032 + 119808 + 32768);        //    718,848 B

  float* out = (float*)d_out;

  k_prep<<<dim3(7562), dim3(256), 0, stream>>>(cids, cemb, xbf, W, wt, relemb, selfemb,
                                               partials, sent, nmask);
  k_gemm<<<dim3(1095), dim3(256), 0, stream>>>(xbf, wt, xw8, partials, relw2, bias,
                                               cids, eidx, eattr, nmask, out);
  k_out<<<dim3(N_TRIPLES / 16), dim3(256), 0, stream>>>(eidx, eattr, xw8, relw2, out);
}

// Round 12
// 96.689 us; speedup vs baseline: 1.2619x; 1.0501x over previous
//
#include <hip/hip_runtime.h>
#include <stdint.h>

#define N_NODES 8192
#define N_EDGES 65536
#define N_TRIPLES (N_EDGES + N_NODES)   // 73728
#define D 768
#define D2 1536
#define NREL 38
#define BATCH 8
#define SENTN 512                        // B*S
#define OUT1_OFF ((size_t)N_TRIPLES * D)                     // 56623104
#define OUT2_OFF (OUT1_OFF + (size_t)BATCH * N_TRIPLES)      // 57212928

typedef __attribute__((ext_vector_type(4))) float f32x4;
typedef __attribute__((ext_vector_type(2))) float f32x2;
typedef __attribute__((ext_vector_type(4))) unsigned short ushort4v;

static __device__ __forceinline__ unsigned short f2bf(float f) {
  unsigned u = __builtin_bit_cast(unsigned, f);
  u += 0x7FFFu + ((u >> 16) & 1u);
  return (unsigned short)(u >> 16);
}

// ================= merged prep (fp8 x + fp8 W13T) =================
__global__ void k_prep(const int* __restrict__ cids, const float* __restrict__ cemb,
                       unsigned char* __restrict__ x8,
                       const float* __restrict__ W, unsigned char* __restrict__ wt8,
                       const float* __restrict__ relemb, const float* __restrict__ selfemb,
                       float* __restrict__ partials,
                       const int* __restrict__ sent, unsigned int* __restrict__ nmask) {
  __shared__ __align__(16) char smraw[32 * 33 * 4];
  int b = blockIdx.x;
  if (b < 6144) {
    int t4 = b * 256 + threadIdx.x;
    int row = t4 / (D / 4);
    int c4 = t4 % (D / 4);
    int cid = cids[row];
    float4 v = ((const float4*)(cemb + (size_t)cid * D))[c4];
    int p = __builtin_amdgcn_cvt_pk_fp8_f32(v.x, v.y, 0, false);
    p = __builtin_amdgcn_cvt_pk_fp8_f32(v.z, v.w, p, true);
    *(int*)(x8 + (size_t)t4 * 4) = p;
  } else if (b < 7296) {
    float (*tile)[33] = (float(*)[33])smraw;
    int idx = b - 6144;
    int kb = (idx % 24) * 32;
    int jb = (idx / 24) * 32;
    int tx = threadIdx.x % 32;
    int ty = threadIdx.x / 32;
#pragma unroll
    for (int i = 0; i < 4; ++i) {
      int k = kb + ty + i * 8;
      int j = jb + tx;
      float v = (j < D) ? W[(size_t)k * D + j] : W[(size_t)(2 * D + k) * D + (j - D)];
      tile[ty + i * 8][tx] = v;
    }
    __syncthreads();
#pragma unroll
    for (int i = 0; i < 4; ++i) {
      int j = jb + ty + i * 8;
      int k = kb + tx;
      float v = tile[tx][ty + i * 8];
      wt8[(size_t)j * D + k] =
          (unsigned char)(__builtin_amdgcn_cvt_pk_fp8_f32(v, v, 0, false) & 0xFF);
    }
  } else if (b < 7530) {
    int idx = b - 7296;        // 0..233
    int r = idx / 6;           // 0..38
    int ch = idx % 6;          // K-chunk of 128
    const float* src = (r < NREL) ? (relemb + (size_t)r * D) : selfemb;
    int c = threadIdx.x;
    const float* W2 = W + (size_t)D * D;
    float a0 = 0.f, a1 = 0.f, a2 = 0.f;
    int k0 = ch * 128;
    for (int k = 0; k < 128; ++k) {
      float s = src[k0 + k];
      const float* wr = W2 + (size_t)(k0 + k) * D;
      a0 += s * wr[c];
      a1 += s * wr[c + 256];
      a2 += s * wr[c + 512];
    }
    float* p = partials + (size_t)idx * D;
    p[c] = a0;
    p[c + 256] = a1;
    p[c + 512] = a2;
  } else {
    int* ls = (int*)smraw;
    for (int i = threadIdx.x; i < SENTN; i += 256) ls[i] = sent[i];
    __syncthreads();
    int n = (b - 7530) * 256 + threadIdx.x;
    int cid = cids[n];
    unsigned m = 0;
#pragma unroll 16
    for (int s = 0; s < SENTN; ++s)
      m |= (ls[s] == cid) ? (1u << (s >> 6)) : 0u;
    nmask[n] = m;
  }
}

// ================= fp8 GEMM + side work =================
// A,B fp8 e4m3: LDS 32KB (was 64) -> 4 blocks/CU; 4 loads/STAGE -> vmcnt(4).
// Same 12-step counted-vmcnt skeleton, same barrier count as the verified R5 loop.
// Swizzle at 16B-pair granularity: src pair ^= (row>>1)&3; read same XOR (2-way banks).
__global__ void k_gemm(const unsigned char* __restrict__ A,
                       const unsigned char* __restrict__ BT,
                       unsigned char* __restrict__ xw8,
                       const float* __restrict__ partials, float* __restrict__ relw2,
                       const float* __restrict__ bias,
                       const int* __restrict__ cids, const int* __restrict__ eidx,
                       const float* __restrict__ eattr, const unsigned* __restrict__ nmask,
                       float* __restrict__ out) {
  __shared__ __align__(16) unsigned char lsAB[2][2][128 * 64];   // [buf][A/B] 32KB
  const int bid = blockIdx.x;
  const int tid = threadIdx.x;

  if (bid >= 768) {
    if (bid < 807) {
      int r = bid - 768;
      int c = tid;
      const float* p = partials + (size_t)r * 6 * D;
#pragma unroll
      for (int j = 0; j < 3; ++j) {
        int cc = c + j * 256;
        float s = 0.f;
#pragma unroll
        for (int ch = 0; ch < 6; ++ch) s += p[(size_t)ch * D + cc];
        relw2[(size_t)r * D + cc] = s;
      }
    } else {
      int t = (bid - 807) * 256 + tid;
      int h, tl;
      float rel;
      if (t < N_EDGES) {
        h = eidx[t];
        tl = eidx[N_EDGES + t];
        rel = (float)(int)eattr[2 * t];
      } else {
        h = t - N_EDGES;
        tl = h;
        rel = (float)NREL;
      }
      float* o2 = out + OUT2_OFF + (size_t)t * 3;
      __builtin_nontemporal_store((float)cids[h], o2 + 0);
      __builtin_nontemporal_store(rel, o2 + 1);
      __builtin_nontemporal_store((float)cids[tl], o2 + 2);
      unsigned m = nmask[h] | nmask[tl];
      float* o1 = out + OUT1_OFF;
#pragma unroll
      for (int bb = 0; bb < BATCH; ++bb)
        __builtin_nontemporal_store(((m >> bb) & 1u) ? 1.0f : 0.0f,
                                    o1 + (size_t)bb * N_TRIPLES + t);
    }
    return;
  }

  const int lane = tid & 63;
  const int wid = tid >> 6;
  const int wr = wid >> 1, wc = wid & 1;

  const int swz = (bid & 7) * 96 + (bid >> 3);
  const int arow0 = (swz / 12) * 128;
  const int bcol0 = (swz % 12) * 128;

  f32x4 acc[4][4] = {};

  // Staging: thread -> row (tid>>2), 16B pair (tid&3), pre-swizzled source pair.
  const int rloc = tid >> 2;                        // 0..63
  const int gpair = (tid & 3) ^ ((rloc >> 1) & 3);  // swizzled source 16B-pair
  const unsigned char* ga = A + (size_t)(arow0 + rloc) * D + gpair * 16;
  const unsigned char* gb = BT + (size_t)(bcol0 + rloc) * D + gpair * 16;

  const int lr = lane & 15;
  const int hi = lane >> 4;            // 0..3: 8B k-chunk within 32-K block
  const int fsw = (lr >> 1) & 3;       // row-derived pair XOR for reads

#define STAGE(BUF, K0)                                                                 \
  {                                                                                    \
    _Pragma("unroll") for (int c = 0; c < 2; ++c) {                                    \
      __builtin_amdgcn_global_load_lds(                                                \
          (const __attribute__((address_space(1))) void*)(ga + (size_t)c * 64 * D + (K0)), \
          (__attribute__((address_space(3))) void*)(&lsAB[BUF][0][c * 4096 + tid * 16]), \
          16, 0, 0);                                                                   \
      __builtin_amdgcn_global_load_lds(                                                \
          (const __attribute__((address_space(1))) void*)(gb + (size_t)c * 64 * D + (K0)), \
          (__attribute__((address_space(3))) void*)(&lsAB[BUF][1][c * 4096 + tid * 16]), \
          16, 0, 0);                                                                   \
    }                                                                                  \
  }

#define COMPUTE(BUF)                                                                   \
  {                                                                                    \
    const unsigned char* sA = lsAB[BUF][0];                                            \
    const unsigned char* sB = lsAB[BUF][1];                                            \
    _Pragma("unroll") for (int kk = 0; kk < 2; ++kk) {                                 \
      const int pair = kk * 2 + (hi >> 1);                                             \
      const int boff = ((pair ^ fsw) * 16) + (hi & 1) * 8;                             \
      long af[4], bfv[4];                                                              \
      _Pragma("unroll") for (int m = 0; m < 4; ++m)                                    \
          af[m] = *(const long*)(sA + (wr * 64 + m * 16 + lr) * 64 + boff);            \
      _Pragma("unroll") for (int n = 0; n < 4; ++n)                                    \
          bfv[n] = *(const long*)(sB + (wc * 64 + n * 16 + lr) * 64 + boff);           \
      _Pragma("unroll") for (int m = 0; m < 4; ++m)                                    \
          _Pragma("unroll") for (int n = 0; n < 4; ++n)                                \
              acc[m][n] = __builtin_amdgcn_mfma_f32_16x16x32_fp8_fp8(af[m], bfv[n],    \
                                                                     acc[m][n], 0, 0, 0); \
    }                                                                                  \
  }

  STAGE(0, 0)
  STAGE(1, 64)
#pragma unroll
  for (int t = 0; t < 12; ++t) {
    if (t < 11) { asm volatile("s_waitcnt vmcnt(4)" ::: "memory"); }
    else        { asm volatile("s_waitcnt vmcnt(0)" ::: "memory"); }
    __builtin_amdgcn_s_barrier();
    if (t & 1) COMPUTE(1) else COMPUTE(0)
    asm volatile("" ::: "memory");
    __builtin_amdgcn_s_barrier();
    if (t + 2 < 12) { if (t & 1) STAGE(1, (t + 2) * 64) else STAGE(0, (t + 2) * 64) }
  }
#undef STAGE
#undef COMPUTE

  // Epilogue: bias fold (cols<768, unscaled term) + fp8 e4m3 pack (same as R11).
  const int crow = hi * 4;
  const int ccol = lr;
  const bool addb = (bcol0 < D);
#pragma unroll
  for (int m = 0; m < 4; ++m) {
    int row = arow0 + wr * 64 + m * 16 + crow;
#pragma unroll
    for (int n = 0; n < 4; ++n) {
      int col = bcol0 + wc * 64 + n * 16 + ccol;
      float bv = addb ? bias[col] : 0.f;
      unsigned char* cp = xw8 + (size_t)row * D2 + col;
      int p01 = __builtin_amdgcn_cvt_pk_fp8_f32(acc[m][n][0] + bv, acc[m][n][1] + bv, 0, false);
      int p23 = __builtin_amdgcn_cvt_pk_fp8_f32(acc[m][n][2] + bv, acc[m][n][3] + bv, 0, false);
      cp[0] = (unsigned char)(p01 & 0xFF);
      cp[(size_t)1 * D2] = (unsigned char)((p01 >> 8) & 0xFF);
      cp[(size_t)2 * D2] = (unsigned char)(p23 & 0xFF);
      cp[(size_t)3 * D2] = (unsigned char)((p23 >> 8) & 0xFF);
    }
  }
}

// ================= encoded output (R11-exact) =================
__global__ void k_out(const int* __restrict__ eidx, const float* __restrict__ eattr,
                      const unsigned char* __restrict__ xw8, const float* __restrict__ relw2,
                      float* __restrict__ out) {
  const int wid = threadIdx.x >> 6;
  const int lane = threadIdx.x & 63;
  const int t0 = blockIdx.x * 16 + wid * 4;

  const unsigned* r1[4];
  const unsigned* r3[4];
  const f32x4* rw[4];
  float w[4];
#pragma unroll
  for (int q = 0; q < 4; ++q) {
    int t = t0 + q;
    if (t < N_EDGES) {
      int h = eidx[t];
      int tl = eidx[N_EDGES + t];
      int rel = (int)eattr[2 * t];
      w[q] = eattr[2 * t + 1];
      r1[q] = (const unsigned*)(xw8 + (size_t)h * D2);
      r3[q] = (const unsigned*)(xw8 + (size_t)tl * D2 + D);
      rw[q] = (const f32x4*)(relw2 + (size_t)rel * D);
    } else {
      int i = t - N_EDGES;
      w[q] = 1.f;
      r1[q] = (const unsigned*)(xw8 + (size_t)i * D2);
      r3[q] = (const unsigned*)(xw8 + (size_t)i * D2 + D);
      rw[q] = (const f32x4*)(relw2 + (size_t)NREL * D);
    }
  }

#pragma unroll
  for (int j = 0; j < 3; ++j) {
    const int c4 = j * 64 + lane;
    unsigned ua[4], ux[4];
    f32x4 c[4];
#pragma unroll
    for (int q = 0; q < 4; ++q) {
      ua[q] = r1[q][c4];
      ux[q] = r3[q][c4];
      c[q] = rw[q][c4];
    }
#pragma unroll
    for (int q = 0; q < 4; ++q) {
      f32x2 alo = __builtin_amdgcn_cvt_pk_f32_fp8(ua[q], false);
      f32x2 ahi = __builtin_amdgcn_cvt_pk_f32_fp8(ua[q], true);
      f32x2 xlo = __builtin_amdgcn_cvt_pk_f32_fp8(ux[q], false);
      f32x2 xhi = __builtin_amdgcn_cvt_pk_f32_fp8(ux[q], true);
      f32x4 res;
      res.x = alo[0] + w[q] * c[q].x + xlo[0];
      res.y = alo[1] + w[q] * c[q].y + xlo[1];
      res.z = ahi[0] + w[q] * c[q].z + xhi[0];
      res.w = ahi[1] + w[q] * c[q].w + xhi[1];
      f32x4* o = (f32x4*)(out + (size_t)(t0 + q) * D);
      __builtin_nontemporal_store(res, &o[c4]);
    }
  }
}

extern "C" void kernel_launch(void* const* d_in, const int* in_sizes, int n_in,
                              void* d_out, int out_size, void* d_ws, size_t ws_size,
                              hipStream_t stream) {
  const int* cids = (const int*)d_in[0];
  const int* eidx = (const int*)d_in[1];
  const float* eattr = (const float*)d_in[2];
  const int* sent = (const int*)d_in[3];
  const float* cemb = (const float*)d_in[4];
  const float* relemb = (const float*)d_in[5];
  const float* selfemb = (const float*)d_in[6];
  const float* W = (const float*)d_in[7];
  const float* bias = (const float*)d_in[8];

  char* ws = (char*)d_ws;
  unsigned char* x8 = (unsigned char*)ws;                        //  6,291,456 B
  unsigned char* wt8 = (unsigned char*)(ws + 6291456);           //  1,179,648 B
  unsigned char* xw8 = (unsigned char*)(ws + 6291456 + 1179648); // 12,582,912 B
  float* relw2 = (float*)(ws + 20054016);                        //    119,808 B
  unsigned* nmask = (unsigned*)(ws + 20054016 + 119808);         //     32,768 B
  float* partials = (float*)(ws + 20054016 + 119808 + 32768);    //    718,848 B

  float* out = (float*)d_out;

  k_prep<<<dim3(7562), dim3(256), 0, stream>>>(cids, cemb, x8, W, wt8, relemb, selfemb,
                                               partials, sent, nmask);
  k_gemm<<<dim3(1095), dim3(256), 0, stream>>>(x8, wt8, xw8, partials, relw2, bias,
                                               cids, eidx, eattr, nmask, out);
  k_out<<<dim3(N_TRIPLES / 16), dim3(256), 0, stream>>>(eidx, eattr, xw8, relw2, out);
}

// Round 13
// 95.695 us; speedup vs baseline: 1.2750x; 1.0104x over previous
//
#include <hip/hip_runtime.h>
#include <stdint.h>

#define N_NODES 8192
#define N_EDGES 65536
#define N_TRIPLES (N_EDGES + N_NODES)   // 73728
#define D 768
#define D2 1536
#define NREL 38
#define BATCH 8
#define SENTN 512                        // B*S
#define OUT1_OFF ((size_t)N_TRIPLES * D)                     // 56623104
#define OUT2_OFF (OUT1_OFF + (size_t)BATCH * N_TRIPLES)      // 57212928

typedef __attribute__((ext_vector_type(4))) float f32x4;
typedef __attribute__((ext_vector_type(2))) float f32x2;
typedef __attribute__((ext_vector_type(4))) unsigned short ushort4v;

static __device__ __forceinline__ unsigned short f2bf(float f) {
  unsigned u = __builtin_bit_cast(unsigned, f);
  u += 0x7FFFu + ((u >> 16) & 1u);
  return (unsigned short)(u >> 16);
}

// ================= merged prep (R12-exact) =================
__global__ void k_prep(const int* __restrict__ cids, const float* __restrict__ cemb,
                       unsigned char* __restrict__ x8,
                       const float* __restrict__ W, unsigned char* __restrict__ wt8,
                       const float* __restrict__ relemb, const float* __restrict__ selfemb,
                       float* __restrict__ partials,
                       const int* __restrict__ sent, unsigned int* __restrict__ nmask) {
  __shared__ __align__(16) char smraw[32 * 33 * 4];
  int b = blockIdx.x;
  if (b < 6144) {
    int t4 = b * 256 + threadIdx.x;
    int row = t4 / (D / 4);
    int c4 = t4 % (D / 4);
    int cid = cids[row];
    float4 v = ((const float4*)(cemb + (size_t)cid * D))[c4];
    int p = __builtin_amdgcn_cvt_pk_fp8_f32(v.x, v.y, 0, false);
    p = __builtin_amdgcn_cvt_pk_fp8_f32(v.z, v.w, p, true);
    *(int*)(x8 + (size_t)t4 * 4) = p;
  } else if (b < 7296) {
    float (*tile)[33] = (float(*)[33])smraw;
    int idx = b - 6144;
    int kb = (idx % 24) * 32;
    int jb = (idx / 24) * 32;
    int tx = threadIdx.x % 32;
    int ty = threadIdx.x / 32;
#pragma unroll
    for (int i = 0; i < 4; ++i) {
      int k = kb + ty + i * 8;
      int j = jb + tx;
      float v = (j < D) ? W[(size_t)k * D + j] : W[(size_t)(2 * D + k) * D + (j - D)];
      tile[ty + i * 8][tx] = v;
    }
    __syncthreads();
#pragma unroll
    for (int i = 0; i < 4; ++i) {
      int j = jb + ty + i * 8;
      int k = kb + tx;
      float v = tile[tx][ty + i * 8];
      wt8[(size_t)j * D + k] =
          (unsigned char)(__builtin_amdgcn_cvt_pk_fp8_f32(v, v, 0, false) & 0xFF);
    }
  } else if (b < 7530) {
    int idx = b - 7296;        // 0..233
    int r = idx / 6;           // 0..38
    int ch = idx % 6;          // K-chunk of 128
    const float* src = (r < NREL) ? (relemb + (size_t)r * D) : selfemb;
    int c = threadIdx.x;
    const float* W2 = W + (size_t)D * D;
    float a0 = 0.f, a1 = 0.f, a2 = 0.f;
    int k0 = ch * 128;
    for (int k = 0; k < 128; ++k) {
      float s = src[k0 + k];
      const float* wr = W2 + (size_t)(k0 + k) * D;
      a0 += s * wr[c];
      a1 += s * wr[c + 256];
      a2 += s * wr[c + 512];
    }
    float* p = partials + (size_t)idx * D;
    p[c] = a0;
    p[c + 256] = a1;
    p[c + 512] = a2;
  } else {
    int* ls = (int*)smraw;
    for (int i = threadIdx.x; i < SENTN; i += 256) ls[i] = sent[i];
    __syncthreads();
    int n = (b - 7530) * 256 + threadIdx.x;
    int cid = cids[n];
    unsigned m = 0;
#pragma unroll 16
    for (int s = 0; s < SENTN; ++s)
      m |= (ls[s] == cid) ? (1u << (s >> 6)) : 0u;
    nmask[n] = m;
  }
}

// ================= fp8 GEMM, 3-buffer ring (ONE barrier/step) =================
// LDS 48KB -> 3 blocks/CU. Prefetch depth 2 tiles (~600cyc cover). Hazard proof:
// top-of-step barrier => all waves finished COMPUTE(t-1) (reads buf[(t-1)%3]);
// STAGE(t+2) targets buf[(t+2)%3]==buf[(t-1)%3] => write-after-read safe.
// vmcnt(4)-then-barrier => all waves' tile-t loads landed before any reads.
__global__ void k_gemm(const unsigned char* __restrict__ A,
                       const unsigned char* __restrict__ BT,
                       unsigned char* __restrict__ xw8,
                       const float* __restrict__ partials, float* __restrict__ relw2,
                       const float* __restrict__ bias,
                       const int* __restrict__ cids, const int* __restrict__ eidx,
                       const float* __restrict__ eattr, const unsigned* __restrict__ nmask,
                       float* __restrict__ out) {
  __shared__ __align__(16) unsigned char lsAB[3][2][128 * 64];   // [buf][A/B] 48KB
  const int bid = blockIdx.x;
  const int tid = threadIdx.x;

  if (bid >= 768) {
    if (bid < 807) {
      int r = bid - 768;
      int c = tid;
      const float* p = partials + (size_t)r * 6 * D;
#pragma unroll
      for (int j = 0; j < 3; ++j) {
        int cc = c + j * 256;
        float s = 0.f;
#pragma unroll
        for (int ch = 0; ch < 6; ++ch) s += p[(size_t)ch * D + cc];
        relw2[(size_t)r * D + cc] = s;
      }
    } else {
      int t = (bid - 807) * 256 + tid;
      int h, tl;
      float rel;
      if (t < N_EDGES) {
        h = eidx[t];
        tl = eidx[N_EDGES + t];
        rel = (float)(int)eattr[2 * t];
      } else {
        h = t - N_EDGES;
        tl = h;
        rel = (float)NREL;
      }
      float* o2 = out + OUT2_OFF + (size_t)t * 3;
      __builtin_nontemporal_store((float)cids[h], o2 + 0);
      __builtin_nontemporal_store(rel, o2 + 1);
      __builtin_nontemporal_store((float)cids[tl], o2 + 2);
      unsigned m = nmask[h] | nmask[tl];
      float* o1 = out + OUT1_OFF;
#pragma unroll
      for (int bb = 0; bb < BATCH; ++bb)
        __builtin_nontemporal_store(((m >> bb) & 1u) ? 1.0f : 0.0f,
                                    o1 + (size_t)bb * N_TRIPLES + t);
    }
    return;
  }

  const int lane = tid & 63;
  const int wid = tid >> 6;
  const int wr = wid >> 1, wc = wid & 1;

  const int swz = (bid & 7) * 96 + (bid >> 3);
  const int arow0 = (swz / 12) * 128;
  const int bcol0 = (swz % 12) * 128;

  f32x4 acc[4][4] = {};

  const int rloc = tid >> 2;                        // 0..63
  const int gpair = (tid & 3) ^ ((rloc >> 1) & 3);  // swizzled source 16B-pair
  const unsigned char* ga = A + (size_t)(arow0 + rloc) * D + gpair * 16;
  const unsigned char* gb = BT + (size_t)(bcol0 + rloc) * D + gpair * 16;

  const int lr = lane & 15;
  const int hi = lane >> 4;
  const int fsw = (lr >> 1) & 3;

#define STAGE(BUF, K0)                                                                 \
  {                                                                                    \
    _Pragma("unroll") for (int c = 0; c < 2; ++c) {                                    \
      __builtin_amdgcn_global_load_lds(                                                \
          (const __attribute__((address_space(1))) void*)(ga + (size_t)c * 64 * D + (K0)), \
          (__attribute__((address_space(3))) void*)(&lsAB[BUF][0][c * 4096 + tid * 16]), \
          16, 0, 0);                                                                   \
      __builtin_amdgcn_global_load_lds(                                                \
          (const __attribute__((address_space(1))) void*)(gb + (size_t)c * 64 * D + (K0)), \
          (__attribute__((address_space(3))) void*)(&lsAB[BUF][1][c * 4096 + tid * 16]), \
          16, 0, 0);                                                                   \
    }                                                                                  \
  }

#define COMPUTE(BUF)                                                                   \
  {                                                                                    \
    const unsigned char* sA = lsAB[BUF][0];                                            \
    const unsigned char* sB = lsAB[BUF][1];                                            \
    _Pragma("unroll") for (int kk = 0; kk < 2; ++kk) {                                 \
      const int pair = kk * 2 + (hi >> 1);                                             \
      const int boff = ((pair ^ fsw) * 16) + (hi & 1) * 8;                             \
      long af[4], bfv[4];                                                              \
      _Pragma("unroll") for (int m = 0; m < 4; ++m)                                    \
          af[m] = *(const long*)(sA + (wr * 64 + m * 16 + lr) * 64 + boff);            \
      _Pragma("unroll") for (int n = 0; n < 4; ++n)                                    \
          bfv[n] = *(const long*)(sB + (wc * 64 + n * 16 + lr) * 64 + boff);           \
      _Pragma("unroll") for (int m = 0; m < 4; ++m)                                    \
          _Pragma("unroll") for (int n = 0; n < 4; ++n)                                \
              acc[m][n] = __builtin_amdgcn_mfma_f32_16x16x32_fp8_fp8(af[m], bfv[n],    \
                                                                     acc[m][n], 0, 0, 0); \
    }                                                                                  \
  }

  // 3-buffer ring: tiles 0..11, buf = t%3, ONE barrier per step.
  STAGE(0, 0)
  STAGE(1, 64)
#pragma unroll
  for (int t = 0; t < 12; ++t) {
    if (t < 11) { asm volatile("s_waitcnt vmcnt(4)" ::: "memory"); }
    else        { asm volatile("s_waitcnt vmcnt(0)" ::: "memory"); }
    __builtin_amdgcn_s_barrier();      // all waves: tile-t loaded, COMPUTE(t-1) done
    switch (t % 3) {
      case 0: COMPUTE(0) break;
      case 1: COMPUTE(1) break;
      case 2: COMPUTE(2) break;
    }
    asm volatile("" ::: "memory");
    if (t + 2 < 12) {
      switch ((t + 2) % 3) {
        case 0: STAGE(0, (t + 2) * 64) break;
        case 1: STAGE(1, (t + 2) * 64) break;
        case 2: STAGE(2, (t + 2) * 64) break;
      }
    }
  }
#undef STAGE
#undef COMPUTE

  // Epilogue: bias fold + fp8 pack (R12-exact).
  const int crow = hi * 4;
  const int ccol = lr;
  const bool addb = (bcol0 < D);
#pragma unroll
  for (int m = 0; m < 4; ++m) {
    int row = arow0 + wr * 64 + m * 16 + crow;
#pragma unroll
    for (int n = 0; n < 4; ++n) {
      int col = bcol0 + wc * 64 + n * 16 + ccol;
      float bv = addb ? bias[col] : 0.f;
      unsigned char* cp = xw8 + (size_t)row * D2 + col;
      int p01 = __builtin_amdgcn_cvt_pk_fp8_f32(acc[m][n][0] + bv, acc[m][n][1] + bv, 0, false);
      int p23 = __builtin_amdgcn_cvt_pk_fp8_f32(acc[m][n][2] + bv, acc[m][n][3] + bv, 0, false);
      cp[0] = (unsigned char)(p01 & 0xFF);
      cp[(size_t)1 * D2] = (unsigned char)((p01 >> 8) & 0xFF);
      cp[(size_t)2 * D2] = (unsigned char)(p23 & 0xFF);
      cp[(size_t)3 * D2] = (unsigned char)((p23 >> 8) & 0xFF);
    }
  }
}

// ================= encoded output (R12-exact) =================
__global__ void k_out(const int* __restrict__ eidx, const float* __restrict__ eattr,
                      const unsigned char* __restrict__ xw8, const float* __restrict__ relw2,
                      float* __restrict__ out) {
  const int wid = threadIdx.x >> 6;
  const int lane = threadIdx.x & 63;
  const int t0 = blockIdx.x * 16 + wid * 4;

  const unsigned* r1[4];
  const unsigned* r3[4];
  const f32x4* rw[4];
  float w[4];
#pragma unroll
  for (int q = 0; q < 4; ++q) {
    int t = t0 + q;
    if (t < N_EDGES) {
      int h = eidx[t];
      int tl = eidx[N_EDGES + t];
      int rel = (int)eattr[2 * t];
      w[q] = eattr[2 * t + 1];
      r1[q] = (const unsigned*)(xw8 + (size_t)h * D2);
      r3[q] = (const unsigned*)(xw8 + (size_t)tl * D2 + D);
      rw[q] = (const f32x4*)(relw2 + (size_t)rel * D);
    } else {
      int i = t - N_EDGES;
      w[q] = 1.f;
      r1[q] = (const unsigned*)(xw8 + (size_t)i * D2);
      r3[q] = (const unsigned*)(xw8 + (size_t)i * D2 + D);
      rw[q] = (const f32x4*)(relw2 + (size_t)NREL * D);
    }
  }

#pragma unroll
  for (int j = 0; j < 3; ++j) {
    const int c4 = j * 64 + lane;
    unsigned ua[4], ux[4];
    f32x4 c[4];
#pragma unroll
    for (int q = 0; q < 4; ++q) {
      ua[q] = r1[q][c4];
      ux[q] = r3[q][c4];
      c[q] = rw[q][c4];
    }
#pragma unroll
    for (int q = 0; q < 4; ++q) {
      f32x2 alo = __builtin_amdgcn_cvt_pk_f32_fp8(ua[q], false);
      f32x2 ahi = __builtin_amdgcn_cvt_pk_f32_fp8(ua[q], true);
      f32x2 xlo = __builtin_amdgcn_cvt_pk_f32_fp8(ux[q], false);
      f32x2 xhi = __builtin_amdgcn_cvt_pk_f32_fp8(ux[q], true);
      f32x4 res;
      res.x = alo[0] + w[q] * c[q].x + xlo[0];
      res.y = alo[1] + w[q] * c[q].y + xlo[1];
      res.z = ahi[0] + w[q] * c[q].z + xhi[0];
      res.w = ahi[1] + w[q] * c[q].w + xhi[1];
      f32x4* o = (f32x4*)(out + (size_t)(t0 + q) * D);
      __builtin_nontemporal_store(res, &o[c4]);
    }
  }
}

extern "C" void kernel_launch(void* const* d_in, const int* in_sizes, int n_in,
                              void* d_out, int out_size, void* d_ws, size_t ws_size,
                              hipStream_t stream) {
  const int* cids = (const int*)d_in[0];
  const int* eidx = (const int*)d_in[1];
  const float* eattr = (const float*)d_in[2];
  const int* sent = (const int*)d_in[3];
  const float* cemb = (const float*)d_in[4];
  const float* relemb = (const float*)d_in[5];
  const float* selfemb = (const float*)d_in[6];
  const float* W = (const float*)d_in[7];
  const float* bias = (const float*)d_in[8];

  char* ws = (char*)d_ws;
  unsigned char* x8 = (unsigned char*)ws;                        //  6,291,456 B
  unsigned char* wt8 = (unsigned char*)(ws + 6291456);           //  1,179,648 B
  unsigned char* xw8 = (unsigned char*)(ws + 6291456 + 1179648); // 12,582,912 B
  float* relw2 = (float*)(ws + 20054016);                        //    119,808 B
  unsigned* nmask = (unsigned*)(ws + 20054016 + 119808);         //     32,768 B
  float* partials = (float*)(ws + 20054016 + 119808 + 32768);    //    718,848 B

  float* out = (float*)d_out;

  k_prep<<<dim3(7562), dim3(256), 0, stream>>>(cids, cemb, x8, W, wt8, relemb, selfemb,
                                               partials, sent, nmask);
  k_gemm<<<dim3(1095), dim3(256), 0, stream>>>(x8, wt8, xw8, partials, relw2, bias,
                                               cids, eidx, eattr, nmask, out);
  k_out<<<dim3(N_TRIPLES / 16), dim3(256), 0, stream>>>(eidx, eattr, xw8, relw2, out);
}

// Round 14
// 94.263 us; speedup vs baseline: 1.2944x; 1.0152x over previous
//
#include <hip/hip_runtime.h>
#include <stdint.h>

#define N_NODES 8192
#define N_EDGES 65536
#define N_TRIPLES (N_EDGES + N_NODES)   // 73728
#define D 768
#define D2 1536
#define NREL 38
#define BATCH 8
#define SENTN 512                        // B*S
#define OUT1_OFF ((size_t)N_TRIPLES * D)                     // 56623104
#define OUT2_OFF (OUT1_OFF + (size_t)BATCH * N_TRIPLES)      // 57212928

typedef __attribute__((ext_vector_type(4))) float f32x4;
typedef __attribute__((ext_vector_type(2))) float f32x2;
typedef __attribute__((ext_vector_type(4))) unsigned short ushort4v;

static __device__ __forceinline__ unsigned short f2bf(float f) {
  unsigned u = __builtin_bit_cast(unsigned, f);
  u += 0x7FFFu + ((u >> 16) & 1u);
  return (unsigned short)(u >> 16);
}

// ================= merged prep (R12 bodies; grid-stride 2048 blocks) =================
__global__ void k_prep(const int* __restrict__ cids, const float* __restrict__ cemb,
                       unsigned char* __restrict__ x8,
                       const float* __restrict__ W, unsigned char* __restrict__ wt8,
                       const float* __restrict__ relemb, const float* __restrict__ selfemb,
                       float* __restrict__ partials,
                       const int* __restrict__ sent, unsigned int* __restrict__ nmask) {
  __shared__ __align__(16) char smraw[32 * 33 * 4];
  for (int b = blockIdx.x; b < 7562; b += 2048) {
    __syncthreads();   // smraw reuse guard between virtual blocks
    if (b < 6144) {
      int t4 = b * 256 + threadIdx.x;
      int row = t4 / (D / 4);
      int c4 = t4 % (D / 4);
      int cid = cids[row];
      float4 v = ((const float4*)(cemb + (size_t)cid * D))[c4];
      int p = __builtin_amdgcn_cvt_pk_fp8_f32(v.x, v.y, 0, false);
      p = __builtin_amdgcn_cvt_pk_fp8_f32(v.z, v.w, p, true);
      *(int*)(x8 + (size_t)t4 * 4) = p;
    } else if (b < 7296) {
      float (*tile)[33] = (float(*)[33])smraw;
      int idx = b - 6144;
      int kb = (idx % 24) * 32;
      int jb = (idx / 24) * 32;
      int tx = threadIdx.x % 32;
      int ty = threadIdx.x / 32;
#pragma unroll
      for (int i = 0; i < 4; ++i) {
        int k = kb + ty + i * 8;
        int j = jb + tx;
        float v = (j < D) ? W[(size_t)k * D + j] : W[(size_t)(2 * D + k) * D + (j - D)];
        tile[ty + i * 8][tx] = v;
      }
      __syncthreads();
#pragma unroll
      for (int i = 0; i < 4; ++i) {
        int j = jb + ty + i * 8;
        int k = kb + tx;
        float v = tile[tx][ty + i * 8];
        wt8[(size_t)j * D + k] =
            (unsigned char)(__builtin_amdgcn_cvt_pk_fp8_f32(v, v, 0, false) & 0xFF);
      }
    } else if (b < 7530) {
      int idx = b - 7296;        // 0..233
      int r = idx / 6;           // 0..38
      int ch = idx % 6;          // K-chunk of 128
      const float* src = (r < NREL) ? (relemb + (size_t)r * D) : selfemb;
      int c = threadIdx.x;
      const float* W2 = W + (size_t)D * D;
      float a0 = 0.f, a1 = 0.f, a2 = 0.f;
      int k0 = ch * 128;
      for (int k = 0; k < 128; ++k) {
        float s = src[k0 + k];
        const float* wr = W2 + (size_t)(k0 + k) * D;
        a0 += s * wr[c];
        a1 += s * wr[c + 256];
        a2 += s * wr[c + 512];
      }
      float* p = partials + (size_t)idx * D;
      p[c] = a0;
      p[c + 256] = a1;
      p[c + 512] = a2;
    } else {
      int* ls = (int*)smraw;
      for (int i = threadIdx.x; i < SENTN; i += 256) ls[i] = sent[i];
      __syncthreads();
      int n = (b - 7530) * 256 + threadIdx.x;
      int cid = cids[n];
      unsigned m = 0;
#pragma unroll 16
      for (int s = 0; s < SENTN; ++s)
        m |= (ls[s] == cid) ? (1u << (s >> 6)) : 0u;
      nmask[n] = m;
    }
  }
}

// ================= fp8 GEMM: 256x128 tile, 8 waves, 2-buffer counted-vmcnt =================
// blocks [0,384): GEMM; [384,423): relw2 reduce; [423,567): ids+mask. 512 thr/block.
// LDS 48KB -> 3 blocks/CU. Barriers per FLOP halved vs 128^2; B refetch halved.
// Bit-identical arithmetic to R13 (same K-order, same fragments) => absmax tripwire.
__global__ void k_gemm(const unsigned char* __restrict__ A,
                       const unsigned char* __restrict__ BT,
                       unsigned char* __restrict__ xw8,
                       const float* __restrict__ partials, float* __restrict__ relw2,
                       const float* __restrict__ bias,
                       const int* __restrict__ cids, const int* __restrict__ eidx,
                       const float* __restrict__ eattr, const unsigned* __restrict__ nmask,
                       float* __restrict__ out) {
  __shared__ __align__(16) unsigned char lsA[2][256 * 64];   // 32KB
  __shared__ __align__(16) unsigned char lsB[2][128 * 64];   // 16KB
  const int bid = blockIdx.x;
  const int tid = threadIdx.x;

  if (bid >= 384) {
    if (bid < 423) {
      int r = bid - 384;
      const float* p = partials + (size_t)r * 6 * D;
#pragma unroll
      for (int j = 0; j < 2; ++j) {
        int cc = tid + j * 512;
        if (cc < D) {
          float s = 0.f;
#pragma unroll
          for (int ch = 0; ch < 6; ++ch) s += p[(size_t)ch * D + cc];
          relw2[(size_t)r * D + cc] = s;
        }
      }
    } else {
      int t = (bid - 423) * 512 + tid;   // 144*512 = 73728 exact
      int h, tl;
      float rel;
      if (t < N_EDGES) {
        h = eidx[t];
        tl = eidx[N_EDGES + t];
        rel = (float)(int)eattr[2 * t];
      } else {
        h = t - N_EDGES;
        tl = h;
        rel = (float)NREL;
      }
      float* o2 = out + OUT2_OFF + (size_t)t * 3;
      __builtin_nontemporal_store((float)cids[h], o2 + 0);
      __builtin_nontemporal_store(rel, o2 + 1);
      __builtin_nontemporal_store((float)cids[tl], o2 + 2);
      unsigned m = nmask[h] | nmask[tl];
      float* o1 = out + OUT1_OFF;
#pragma unroll
      for (int bb = 0; bb < BATCH; ++bb)
        __builtin_nontemporal_store(((m >> bb) & 1u) ? 1.0f : 0.0f,
                                    o1 + (size_t)bb * N_TRIPLES + t);
    }
    return;
  }

  const int lane = tid & 63;
  const int wid = tid >> 6;           // 0..7
  const int wr = wid >> 1;            // 0..3 -> 64-row band of 256
  const int wc = wid & 1;             // 0..1 -> 64-col band of 128

  // XCD swizzle: 384 GEMM blocks = 8 x 48.
  const int swz = (bid & 7) * 48 + (bid >> 3);
  const int arow0 = (swz / 12) * 256;
  const int bcol0 = (swz % 12) * 128;

  f32x4 acc[4][4] = {};

  // Staging (dest lane-linear): dest(row=c*128+(t>>2), pair=t&3) <- src pair (t&3)^((t>>3)&3).
  const int gpair = (tid & 3) ^ ((tid >> 3) & 3);
  const unsigned char* ga = A + (size_t)(arow0 + (tid >> 2)) * D + gpair * 16;
  const unsigned char* gb = BT + (size_t)(bcol0 + (tid >> 2)) * D + gpair * 16;

  const int lr = lane & 15;
  const int hi = lane >> 4;
  const int fsw = (lr >> 1) & 3;

#define STAGE(BUF, K0)                                                                 \
  {                                                                                    \
    _Pragma("unroll") for (int c = 0; c < 2; ++c)                                      \
      __builtin_amdgcn_global_load_lds(                                                \
          (const __attribute__((address_space(1))) void*)(ga + (size_t)c * 128 * D + (K0)), \
          (__attribute__((address_space(3))) void*)(&lsA[BUF][c * 8192 + tid * 16]),   \
          16, 0, 0);                                                                   \
    __builtin_amdgcn_global_load_lds(                                                  \
        (const __attribute__((address_space(1))) void*)(gb + (K0)),                    \
        (__attribute__((address_space(3))) void*)(&lsB[BUF][tid * 16]), 16, 0, 0);     \
  }

#define COMPUTE(BUF)                                                                   \
  {                                                                                    \
    const unsigned char* sA = lsA[BUF];                                                \
    const unsigned char* sB = lsB[BUF];                                                \
    _Pragma("unroll") for (int kk = 0; kk < 2; ++kk) {                                 \
      const int pair = kk * 2 + (hi >> 1);                                             \
      const int boff = ((pair ^ fsw) * 16) + (hi & 1) * 8;                             \
      long af[4], bfv[4];                                                              \
      _Pragma("unroll") for (int m = 0; m < 4; ++m)                                    \
          af[m] = *(const long*)(sA + (wr * 64 + m * 16 + lr) * 64 + boff);            \
      _Pragma("unroll") for (int n = 0; n < 4; ++n)                                    \
          bfv[n] = *(const long*)(sB + (wc * 64 + n * 16 + lr) * 64 + boff);           \
      _Pragma("unroll") for (int m = 0; m < 4; ++m)                                    \
          _Pragma("unroll") for (int n = 0; n < 4; ++n)                                \
              acc[m][n] = __builtin_amdgcn_mfma_f32_16x16x32_fp8_fp8(af[m], bfv[n],    \
                                                                     acc[m][n], 0, 0, 0); \
    }                                                                                  \
  }

  // 12 K-steps of 64; 3 loads/thread/STAGE -> steady in-flight 6, vmcnt(3).
  STAGE(0, 0)
  STAGE(1, 64)
#pragma unroll
  for (int t = 0; t < 12; ++t) {
    if (t < 11) { asm volatile("s_waitcnt vmcnt(3)" ::: "memory"); }
    else        { asm volatile("s_waitcnt vmcnt(0)" ::: "memory"); }
    __builtin_amdgcn_s_barrier();      // tile t ready in all waves
    if (t & 1) COMPUTE(1) else COMPUTE(0)
    asm volatile("" ::: "memory");
    __builtin_amdgcn_s_barrier();      // all waves done reading buf (t&1)
    if (t + 2 < 12) { if (t & 1) STAGE(1, (t + 2) * 64) else STAGE(0, (t + 2) * 64) }
  }
#undef STAGE
#undef COMPUTE

  // Epilogue: bias fold + fp8 pack (unchanged arithmetic).
  const int crow = hi * 4;
  const bool addb = (bcol0 < D);
#pragma unroll
  for (int m = 0; m < 4; ++m) {
    int row = arow0 + wr * 64 + m * 16 + crow;
#pragma unroll
    for (int n = 0; n < 4; ++n) {
      int col = bcol0 + wc * 64 + n * 16 + lr;
      float bv = addb ? bias[col] : 0.f;
      unsigned char* cp = xw8 + (size_t)row * D2 + col;
      int p01 = __builtin_amdgcn_cvt_pk_fp8_f32(acc[m][n][0] + bv, acc[m][n][1] + bv, 0, false);
      int p23 = __builtin_amdgcn_cvt_pk_fp8_f32(acc[m][n][2] + bv, acc[m][n][3] + bv, 0, false);
      cp[0] = (unsigned char)(p01 & 0xFF);
      cp[(size_t)1 * D2] = (unsigned char)((p01 >> 8) & 0xFF);
      cp[(size_t)2 * D2] = (unsigned char)(p23 & 0xFF);
      cp[(size_t)3 * D2] = (unsigned char)((p23 >> 8) & 0xFF);
    }
  }
}

// ================= encoded output (R12-exact) =================
__global__ void k_out(const int* __restrict__ eidx, const float* __restrict__ eattr,
                      const unsigned char* __restrict__ xw8, const float* __restrict__ relw2,
                      float* __restrict__ out) {
  const int wid = threadIdx.x >> 6;
  const int lane = threadIdx.x & 63;
  const int t0 = blockIdx.x * 16 + wid * 4;

  const unsigned* r1[4];
  const unsigned* r3[4];
  const f32x4* rw[4];
  float w[4];
#pragma unroll
  for (int q = 0; q < 4; ++q) {
    int t = t0 + q;
    if (t < N_EDGES) {
      int h = eidx[t];
      int tl = eidx[N_EDGES + t];
      int rel = (int)eattr[2 * t];
      w[q] = eattr[2 * t + 1];
      r1[q] = (const unsigned*)(xw8 + (size_t)h * D2);
      r3[q] = (const unsigned*)(xw8 + (size_t)tl * D2 + D);
      rw[q] = (const f32x4*)(relw2 + (size_t)rel * D);
    } else {
      int i = t - N_EDGES;
      w[q] = 1.f;
      r1[q] = (const unsigned*)(xw8 + (size_t)i * D2);
      r3[q] = (const unsigned*)(xw8 + (size_t)i * D2 + D);
      rw[q] = (const f32x4*)(relw2 + (size_t)NREL * D);
    }
  }

#pragma unroll
  for (int j = 0; j < 3; ++j) {
    const int c4 = j * 64 + lane;
    unsigned ua[4], ux[4];
    f32x4 c[4];
#pragma unroll
    for (int q = 0; q < 4; ++q) {
      ua[q] = r1[q][c4];
      ux[q] = r3[q][c4];
      c[q] = rw[q][c4];
    }
#pragma unroll
    for (int q = 0; q < 4; ++q) {
      f32x2 alo = __builtin_amdgcn_cvt_pk_f32_fp8(ua[q], false);
      f32x2 ahi = __builtin_amdgcn_cvt_pk_f32_fp8(ua[q], true);
      f32x2 xlo = __builtin_amdgcn_cvt_pk_f32_fp8(ux[q], false);
      f32x2 xhi = __builtin_amdgcn_cvt_pk_f32_fp8(ux[q], true);
      f32x4 res;
      res.x = alo[0] + w[q] * c[q].x + xlo[0];
      res.y = alo[1] + w[q] * c[q].y + xlo[1];
      res.z = ahi[0] + w[q] * c[q].z + xhi[0];
      res.w = ahi[1] + w[q] * c[q].w + xhi[1];
      f32x4* o = (f32x4*)(out + (size_t)(t0 + q) * D);
      __builtin_nontemporal_store(res, &o[c4]);
    }
  }
}

extern "C" void kernel_launch(void* const* d_in, const int* in_sizes, int n_in,
                              void* d_out, int out_size, void* d_ws, size_t ws_size,
                              hipStream_t stream) {
  const int* cids = (const int*)d_in[0];
  const int* eidx = (const int*)d_in[1];
  const float* eattr = (const float*)d_in[2];
  const int* sent = (const int*)d_in[3];
  const float* cemb = (const float*)d_in[4];
  const float* relemb = (const float*)d_in[5];
  const float* selfemb = (const float*)d_in[6];
  const float* W = (const float*)d_in[7];
  const float* bias = (const float*)d_in[8];

  char* ws = (char*)d_ws;
  unsigned char* x8 = (unsigned char*)ws;                        //  6,291,456 B
  unsigned char* wt8 = (unsigned char*)(ws + 6291456);           //  1,179,648 B
  unsigned char* xw8 = (unsigned char*)(ws + 6291456 + 1179648); // 12,582,912 B
  float* relw2 = (float*)(ws + 20054016);                        //    119,808 B
  unsigned* nmask = (unsigned*)(ws + 20054016 + 119808);         //     32,768 B
  float* partials = (float*)(ws + 20054016 + 119808 + 32768);    //    718,848 B

  float* out = (float*)d_out;

  k_prep<<<dim3(2048), dim3(256), 0, stream>>>(cids, cemb, x8, W, wt8, relemb, selfemb,
                                               partials, sent, nmask);
  k_gemm<<<dim3(567), dim3(512), 0, stream>>>(x8, wt8, xw8, partials, relw2, bias,
                                              cids, eidx, eattr, nmask, out);
  k_out<<<dim3(N_TRIPLES / 16), dim3(256), 0, stream>>>(eidx, eattr, xw8, relw2, out);
}